// Round 6
// baseline (228.612 us; speedup 1.0000x reference)
//
#include <hip/hip_runtime.h>
#include <hip/hip_bf16.h>

// Problem: B=2, N=2048, C=1024, H=16, D=64, CHUNK=128, nk=16
// out = ( sum_chunks softmax_chunk( (xWq)(xWk)^T * D^-0.5 ) (xWv) ) Wp + bp

typedef __attribute__((ext_vector_type(4))) float f32x4;
typedef __attribute__((ext_vector_type(8))) short short8;  // 8 bf16 = 4 VGPRs

static __device__ __forceinline__ unsigned short f2bfu(float f) {
    union { __hip_bfloat16 b; unsigned short u; } cv;
    cv.b = __float2bfloat16(f);
    return cv.u;
}
static __device__ __forceinline__ __hip_bfloat16 f2bf(float f) {
    return __float2bfloat16(f);
}
// pack hi16(a),hi16(b) with round-half-up: 2 adds + 1 v_perm (vs ~11 ops for RNE pair)
static __device__ __forceinline__ unsigned int pkrnd(float a, float b) {
    union { float f; unsigned int u; } ua, ub;
    ua.f = a; ub.f = b;
    return __builtin_amdgcn_perm(ub.u + 0x8000u, ua.u + 0x8000u, 0x07060302u);
}
// async global->LDS DMA, 16B per lane, lands at wave-uniform lds base + lane*16
static __device__ __forceinline__ void gload_lds16(const __hip_bfloat16* g, __hip_bfloat16* l) {
    __builtin_amdgcn_global_load_lds(
        (const __attribute__((address_space(1))) void*)g,
        (__attribute__((address_space(3))) void*)l, 16, 0, 0);
}

// ---------------- fused conversion kernel ----------------
// blocks [0,4096): x fp32->bf16 (float4/thread). blocks [4096,8192): W->W^T bf16.
__global__ __launch_bounds__(256) void conv_fused_kernel(
    const float* __restrict__ x, __hip_bfloat16* __restrict__ xb,
    const float* __restrict__ w0, const float* __restrict__ w1,
    const float* __restrict__ w2, const float* __restrict__ w3,
    __hip_bfloat16* __restrict__ wt) {
    const int t = threadIdx.x;
    if (blockIdx.x < 4096) {
        int i = blockIdx.x * 256 + t;
        float4 v = ((const float4*)x)[i];
        ushort4 o;
        o.x = f2bfu(v.x); o.y = f2bfu(v.y); o.z = f2bfu(v.z); o.w = f2bfu(v.w);
        ((ushort4*)xb)[i] = o;
    } else {
        __shared__ float tile[32][33];
        int zz = blockIdx.x - 4096;
        int z = zz >> 10, byi = (zz >> 5) & 31, bxi = zz & 31;
        const float* W = (z == 0) ? w0 : (z == 1) ? w1 : (z == 2) ? w2 : w3;
        __hip_bfloat16* out = wt + (size_t)z * 1048576;
        const int tx = t & 31, ty = t >> 5;  // 32 x 8
        const int r0 = byi * 32, c0 = bxi * 32;
        for (int j = 0; j < 4; ++j)
            tile[ty + j * 8][tx] = W[(size_t)(r0 + ty + j * 8) * 1024 + c0 + tx];
        __syncthreads();
        for (int j = 0; j < 4; ++j)
            out[(size_t)(c0 + ty + j * 8) * 1024 + r0 + tx] = f2bf(tile[tx][ty + j * 8]);
    }
}

// ---------------- QKV GEMM (global_load_lds + XOR-swizzled LDS, m97 shape) ----------------
// z=0 -> q_ws (pre-scaled by D^-0.5*log2e), z=1 -> k_ws, z=2 -> vT_ws [B,H,D,Nperm].
// LDS tiles 128x32 unpadded; physical chunk p of row r holds logical chunk p^((r>>1)&3).
__global__ __launch_bounds__(256) void gemm_qkv_kernel(
    const __hip_bfloat16* __restrict__ A, const __hip_bfloat16* __restrict__ WT,
    __hip_bfloat16* __restrict__ q_ws, __hip_bfloat16* __restrict__ k_ws,
    __hip_bfloat16* __restrict__ vT_ws) {
    const int t = threadIdx.x;
    const int lane = t & 63, w = t >> 6;
    const int quad = lane >> 4, l16 = lane & 15;
    const int wm = w >> 1, wn = w & 1;
    const int n0 = blockIdx.x * 128, m0 = blockIdx.y * 128;
    const int z = blockIdx.z;
    const __hip_bfloat16* Bt = WT + (size_t)z * 1048576;

    __shared__ __align__(16) __hip_bfloat16 As[128 * 32];
    __shared__ __align__(16) __hip_bfloat16 Bs[128 * 32];

    const int rS = t >> 2;                                   // inst 0 row (inst1: +64)
    const int cS = ((t & 3) ^ ((t >> 3) & 3)) * 8;           // lane-constant swizzled chunk
    const __hip_bfloat16* gA = A + (size_t)(m0 + rS) * 1024 + cS;
    const __hip_bfloat16* gB = Bt + (size_t)(n0 + rS) * 1024 + cS;
    __hip_bfloat16* lA = As + (t & 192) * 8;                 // wave base, inst0
    __hip_bfloat16* lB = Bs + (t & 192) * 8;
    const int csw = (quad ^ ((l16 >> 1) & 3)) * 8;           // frag-read swizzled chunk

    f32x4 acc[4][4];
    const f32x4 z4 = {0.f, 0.f, 0.f, 0.f};
    for (int i = 0; i < 4; ++i)
        for (int j = 0; j < 4; ++j) acc[i][j] = z4;

    for (int kk = 0; kk < 32; ++kk) {
        const int k0 = kk * 32;
        __syncthreads();
        gload_lds16(gA + k0, lA);
        gload_lds16(gA + 64 * 1024 + k0, lA + 256 * 8);
        gload_lds16(gB + k0, lB);
        gload_lds16(gB + 64 * 1024 + k0, lB + 256 * 8);
        __syncthreads();
        short8 af[4], bf[4];
        for (int i = 0; i < 4; ++i)
            af[i] = *(const short8*)(As + (wm * 64 + i * 16 + l16) * 32 + csw);
        for (int j = 0; j < 4; ++j)
            bf[j] = *(const short8*)(Bs + (wn * 64 + j * 16 + l16) * 32 + csw);
        for (int i = 0; i < 4; ++i)
            for (int j = 0; j < 4; ++j)
                acc[i][j] = __builtin_amdgcn_mfma_f32_16x16x32_bf16(af[i], bf[j], acc[i][j], 0, 0, 0);
    }

    const int r0 = m0 + wm * 64, c0 = n0 + wn * 64;
    if (z < 2) {
        const float sc = (z == 0) ? 0.18033688f : 1.0f;  // 0.125 * log2(e)
        __hip_bfloat16* dst = (z == 0) ? q_ws : k_ws;
        for (int i = 0; i < 4; ++i) {
            int rowb = r0 + i * 16 + quad * 4;
            for (int j = 0; j < 4; ++j) {
                int col = c0 + j * 16 + l16;
                for (int rg = 0; rg < 4; ++rg)
                    dst[(size_t)(rowb + rg) * 1024 + col] = f2bf(acc[i][j][rg] * sc);
            }
        }
    } else {
        // token c (within 128-chunk) -> V column (c&~31)|(((c>>2)&3)<<3)|(((c>>4)&1)<<2)|(c&3)
        int b = r0 >> 11;
        for (int i = 0; i < 4; ++i) {
            int n_ = (r0 + i * 16 + quad * 4) & 2047;
            int nb = n_ & ~127;
            int c = n_ & 127;  // c&3 == 0 here
            int vcol = (c & ~31) | (((c >> 2) & 3) << 3) | (((c >> 4) & 1) << 2);
            for (int j = 0; j < 4; ++j) {
                int col = c0 + j * 16 + l16;
                int h = col >> 6, d = col & 63;
                ushort4 o;
                o.x = f2bfu(acc[i][j][0]); o.y = f2bfu(acc[i][j][1]);
                o.z = f2bfu(acc[i][j][2]); o.w = f2bfu(acc[i][j][3]);
                *(ushort4*)(vT_ws + (size_t)((b * 16 + h) * 64 + d) * 2048 + nb + vcol) = o;
            }
        }
    }
}

// ---------------- final GEMM (64-row tiles, DMA staging, fp32 out + bias) ----------------
__global__ __launch_bounds__(256) void gemm_final_kernel(
    const __hip_bfloat16* __restrict__ A, const __hip_bfloat16* __restrict__ Bt,
    float* __restrict__ outF, const float* __restrict__ bias) {
    const int t = threadIdx.x;
    const int lane = t & 63, w = t >> 6;
    const int quad = lane >> 4, l16 = lane & 15;
    const int n0 = blockIdx.x * 128, m0 = blockIdx.y * 64;

    __shared__ __align__(16) __hip_bfloat16 As[64 * 32];
    __shared__ __align__(16) __hip_bfloat16 Bs[128 * 32];

    const int rS = t >> 2;
    const int cS = ((t & 3) ^ ((t >> 3) & 3)) * 8;
    const __hip_bfloat16* gA = A + (size_t)(m0 + rS) * 1024 + cS;
    const __hip_bfloat16* gB = Bt + (size_t)(n0 + rS) * 1024 + cS;
    __hip_bfloat16* lA = As + (t & 192) * 8;
    __hip_bfloat16* lB = Bs + (t & 192) * 8;
    const int csw = (quad ^ ((l16 >> 1) & 3)) * 8;

    f32x4 acc[4][2];
    const f32x4 z4 = {0.f, 0.f, 0.f, 0.f};
    for (int i = 0; i < 4; ++i)
        for (int j = 0; j < 2; ++j) acc[i][j] = z4;

    for (int kk = 0; kk < 32; ++kk) {
        const int k0 = kk * 32;
        __syncthreads();
        gload_lds16(gA + k0, lA);
        gload_lds16(gB + k0, lB);
        gload_lds16(gB + 64 * 1024 + k0, lB + 256 * 8);
        __syncthreads();
        short8 af[4], bf[2];
        for (int i = 0; i < 4; ++i)
            af[i] = *(const short8*)(As + (i * 16 + l16) * 32 + csw);
        for (int j = 0; j < 2; ++j)
            bf[j] = *(const short8*)(Bs + (w * 32 + j * 16 + l16) * 32 + csw);
        for (int i = 0; i < 4; ++i)
            for (int j = 0; j < 2; ++j)
                acc[i][j] = __builtin_amdgcn_mfma_f32_16x16x32_bf16(af[i], bf[j], acc[i][j], 0, 0, 0);
    }

    for (int i = 0; i < 4; ++i) {
        int rowb = m0 + i * 16 + quad * 4;
        for (int j = 0; j < 2; ++j) {
            int col = n0 + w * 32 + j * 16 + l16;
            float bv = bias[col];
            for (int rg = 0; rg < 4; ++rg)
                outF[(size_t)(rowb + rg) * 1024 + col] = acc[i][j][rg] + bv;
        }
    }
}

// ---------------- fused attention (2x2 wave split: q-half x key-half) ----------------
// grid (16 q-tiles of 128, 32 bh), block 256 (4 waves). Wave (qg=w&1, kg=w>>1):
// 64 q x 64 keys per chunk -> each wave reads only HALF of K and V frags (8+8 b128
// vs 32 before). Per-chunk softmax denominator: in-register reduce over the wave's
// 64 keys + tiny LDS exchange between kg-pairs (ps). O partial per kg; cross-wave
// add once in the epilogue. K/V tiles unpadded + XOR-swizzled (staging writes hit
// the 8/bank minimum; K-frag reads 2-way (free), V-frag reads conflict-free).
__global__ __launch_bounds__(256, 2) void attn_kernel(
    const __hip_bfloat16* __restrict__ q_ws, const __hip_bfloat16* __restrict__ k_ws,
    const __hip_bfloat16* __restrict__ vT_ws, __hip_bfloat16* __restrict__ attn_ws) {
    const int t = threadIdx.x, lane = t & 63, w = t >> 6;
    const int quad = lane >> 4, l16 = lane & 15;
    const int qg = w & 1, kg = w >> 1;
    const int qt = blockIdx.x;   // 0..15 (128 q each)
    const int bh = blockIdx.y;   // 0..31
    const int b = bh >> 4, h = bh & 15;
    const int q0 = qt * 128;

    // buf c (c=0,1): Ks @ c*32768 [128][64] (swz p=c^(r&7)), Vt @ c*32768+16384 [64][128]
    // (swz p=c^(r&15)); ps @ 65536: float[kg2][8][16]
    __shared__ __align__(16) char smem[66048];
    float* ps = (float*)(smem + 65536);

    // staging lane constants
    const int sgK = t & 7, rKl = t >> 3;    // K rows rKl + it*32
    const int pK = sgK ^ (rKl & 7);
    const int sgV = t & 15, rVl = t >> 4;   // V rows rVl + it*16
    const int pV = sgV ^ (rVl & 15);
    const __hip_bfloat16* gK = k_ws + (size_t)(b * 2048) * 1024 + h * 64;
    const __hip_bfloat16* gV = vT_ws + (size_t)(bh * 64) * 2048;

    // Q fragments (B-operand of S^T = K Q^T): 4 q-tiles x 2 k-blocks, register-resident
    short8 qf[4][2];
#pragma unroll
    for (int j = 0; j < 4; ++j)
#pragma unroll
        for (int kt = 0; kt < 2; ++kt)
            qf[j][kt] = *(const short8*)(q_ws + (size_t)(b * 2048 + q0 + qg * 64 + j * 16 + l16) * 1024 + h * 64 + kt * 32 + quad * 8);

    const f32x4 z4 = {0.f, 0.f, 0.f, 0.f};
    f32x4 O[4][4];  // O^T partial (this wave's 64 keys): [q-tile j][d-tile dt]
#pragma unroll
    for (int j = 0; j < 4; ++j)
#pragma unroll
        for (int dt = 0; dt < 4; ++dt) O[j][dt] = z4;

    // ---- stage chunk 0 into buffer 0 ----
    {
        __hip_bfloat16* Ks0 = (__hip_bfloat16*)smem;
        __hip_bfloat16* Vt0 = (__hip_bfloat16*)(smem + 16384);
#pragma unroll
        for (int it = 0; it < 4; ++it) {
            int r = it * 32 + rKl;
            uint4 v = *(const uint4*)(gK + (size_t)r * 1024 + sgK * 8);
            *(uint4*)(Ks0 + r * 64 + pK * 8) = v;
        }
#pragma unroll
        for (int it = 0; it < 4; ++it) {
            int r = it * 16 + rVl;
            uint4 v = *(const uint4*)(gV + (size_t)r * 2048 + sgV * 8);
            *(uint4*)(Vt0 + r * 128 + pV * 8) = v;
        }
    }
    __syncthreads();

    for (int ck = 0; ck < 16; ++ck) {
        const int cur = ck & 1;
        __hip_bfloat16* Ks = (__hip_bfloat16*)(smem + cur * 32768);
        __hip_bfloat16* Vt = (__hip_bfloat16*)(smem + cur * 32768 + 16384);

        // issue next-chunk global loads now; ds_writes happen after barrier #1
        uint4 stK[4], stV[4];
        if (ck < 15) {
#pragma unroll
            for (int it = 0; it < 4; ++it)
                stK[it] = *(const uint4*)(gK + (size_t)((ck + 1) * 128 + it * 32 + rKl) * 1024 + sgK * 8);
#pragma unroll
            for (int it = 0; it < 4; ++it)
                stV[it] = *(const uint4*)(gV + (size_t)(it * 16 + rVl) * 2048 + (ck + 1) * 128 + sgV * 8);
        }

        // S^T = K Q^T : this wave's 4 key-tiles x 4 q-tiles, K-dim 64
        f32x4 s[4][4];
#pragma unroll
        for (int j = 0; j < 4; ++j)
#pragma unroll
            for (int i = 0; i < 4; ++i) s[j][i] = z4;
#pragma unroll
        for (int kt = 0; kt < 2; ++kt) {
            short8 kf[4];
#pragma unroll
            for (int i = 0; i < 4; ++i)
                kf[i] = *(const short8*)(Ks + (kg * 64 + i * 16 + l16) * 64 + (((kt * 4 + quad) ^ (l16 & 7)) * 8));
#pragma unroll
            for (int i = 0; i < 4; ++i)
#pragma unroll
                for (int j = 0; j < 4; ++j)
                    s[j][i] = __builtin_amdgcn_mfma_f32_16x16x32_bf16(kf[i], qf[j][kt], s[j][i], 0, 0, 0);
        }

        // exp (no max-sub: args bounded ~|4|), in-wave sum over this wave's 64 keys
        float own[4];
#pragma unroll
        for (int j = 0; j < 4; ++j) {
            float sum = 0.f;
#pragma unroll
            for (int i = 0; i < 4; ++i) {
                f32x4 p;
                p[0] = __builtin_amdgcn_exp2f(s[j][i][0]);
                p[1] = __builtin_amdgcn_exp2f(s[j][i][1]);
                p[2] = __builtin_amdgcn_exp2f(s[j][i][2]);
                p[3] = __builtin_amdgcn_exp2f(s[j][i][3]);
                s[j][i] = p;
                sum += (p[0] + p[1]) + (p[2] + p[3]);
            }
            sum += __shfl_xor(sum, 16, 64);
            sum += __shfl_xor(sum, 32, 64);
            own[j] = sum;
        }
        if (quad == 0) {
#pragma unroll
            for (int j = 0; j < 4; ++j)
                ps[(kg * 8 + qg * 4 + j) * 16 + l16] = own[j];
        }
        __syncthreads();  // #1: ps visible; staging below targets the other buffer

        if (ck < 15) {
            __hip_bfloat16* Ksn = (__hip_bfloat16*)(smem + (cur ^ 1) * 32768);
            __hip_bfloat16* Vtn = (__hip_bfloat16*)(smem + (cur ^ 1) * 32768 + 16384);
#pragma unroll
            for (int it = 0; it < 4; ++it)
                *(uint4*)(Ksn + (it * 32 + rKl) * 64 + pK * 8) = stK[it];
#pragma unroll
            for (int it = 0; it < 4; ++it)
                *(uint4*)(Vtn + (it * 16 + rVl) * 128 + pV * 8) = stV[it];
        }

        float inv[4];
#pragma unroll
        for (int j = 0; j < 4; ++j)
            inv[j] = 1.0f / (own[j] + ps[((kg ^ 1) * 8 + qg * 4 + j) * 16 + l16]);

        // O^T += V^T P^T over this wave's 64 keys (2 K-blocks of 32)
#pragma unroll
        for (int ktl = 0; ktl < 2; ++ktl) {
            short8 bfr[4];
#pragma unroll
            for (int j = 0; j < 4; ++j) {
                const int i0 = 2 * ktl, i1 = 2 * ktl + 1;
                union { uint4 u; short8 s8; } bb;
                bb.u.x = pkrnd(s[j][i0][0] * inv[j], s[j][i0][1] * inv[j]);
                bb.u.y = pkrnd(s[j][i0][2] * inv[j], s[j][i0][3] * inv[j]);
                bb.u.z = pkrnd(s[j][i1][0] * inv[j], s[j][i1][1] * inv[j]);
                bb.u.w = pkrnd(s[j][i1][2] * inv[j], s[j][i1][3] * inv[j]);
                bfr[j] = bb.s8;
            }
#pragma unroll
            for (int dt = 0; dt < 4; ++dt) {
                short8 vf = *(const short8*)(Vt + (dt * 16 + l16) * 128 + ((((kg * 2 + ktl) * 4 + quad) ^ l16) * 8));
#pragma unroll
                for (int j = 0; j < 4; ++j)
                    O[j][dt] = __builtin_amdgcn_mfma_f32_16x16x32_bf16(vf, bfr[j], O[j][dt], 0, 0, 0);
            }
        }
        __syncthreads();  // #2: next-buf staging complete; cur reads complete
    }

    // ---- epilogue: cross-kg O add, then LDS transpose to row-major ----
    if (kg == 1) {
        float* Of = (float*)(smem + qg * 16384);
#pragma unroll
        for (int dt = 0; dt < 4; ++dt)
#pragma unroll
            for (int j = 0; j < 4; ++j)
                *(f32x4*)(Of + ((size_t)((dt * 4 + j) * 64 + quad * 16 + l16)) * 4) = O[j][dt];
    }
    __syncthreads();
    if (kg == 0) {
        float* Of = (float*)(smem + qg * 16384);
        __hip_bfloat16* T = (__hip_bfloat16*)(smem + 32768);  // [128][72]
#pragma unroll
        for (int dt = 0; dt < 4; ++dt)
#pragma unroll
            for (int j = 0; j < 4; ++j) {
                f32x4 o2 = *(const f32x4*)(Of + ((size_t)((dt * 4 + j) * 64 + quad * 16 + l16)) * 4);
                f32x4 oo = O[j][dt] + o2;
                unsigned int w0 = pkrnd(oo[0], oo[1]);
                unsigned int w1 = pkrnd(oo[2], oo[3]);
                int r = qg * 64 + j * 16 + l16;
                *(unsigned int*)(T + r * 72 + dt * 16 + quad * 4) = w0;
                *(unsigned int*)(T + r * 72 + dt * 16 + quad * 4 + 2) = w1;
            }
    }
    __syncthreads();
    {
        const __hip_bfloat16* T = (const __hip_bfloat16*)(smem + 32768);
#pragma unroll
        for (int it = 0; it < 4; ++it) {
            int idx = it * 256 + t;
            int q = idx >> 3, seg = idx & 7;
            uint4 vv = *(const uint4*)(T + q * 72 + seg * 8);
            *(uint4*)(attn_ws + (size_t)(b * 2048 + q0 + q) * 1024 + h * 64 + seg * 8) = vv;
        }
    }
}

// ---------------- launch ----------------
extern "C" void kernel_launch(void* const* d_in, const int* in_sizes, int n_in,
                              void* d_out, int out_size, void* d_ws, size_t ws_size,
                              hipStream_t stream) {
    const float* x  = (const float*)d_in[0];
    const float* Wq = (const float*)d_in[1];
    const float* Wk = (const float*)d_in[2];
    const float* Wv = (const float*)d_in[3];
    const float* Wp = (const float*)d_in[4];
    const float* bp = (const float*)d_in[5];
    float* out = (float*)d_out;

    char* ws = (char*)d_ws;
    __hip_bfloat16* xb    = (__hip_bfloat16*)(ws);              // 8 MB
    __hip_bfloat16* wT    = (__hip_bfloat16*)(ws + 8388608);    // 8 MB
    __hip_bfloat16* q_ws  = (__hip_bfloat16*)(ws + 16777216);   // 8 MB (pre-scaled)
    __hip_bfloat16* k_ws  = (__hip_bfloat16*)(ws + 25165824);   // 8 MB
    __hip_bfloat16* vT_ws = (__hip_bfloat16*)(ws + 33554432);   // 8 MB [B,H,D,Nperm]
    __hip_bfloat16* at_ws = (__hip_bfloat16*)(ws + 41943040);   // 8 MB

    conv_fused_kernel<<<8192, 256, 0, stream>>>(x, xb, Wq, Wk, Wv, Wp, wT);
    gemm_qkv_kernel<<<dim3(8, 32, 3), 256, 0, stream>>>(xb, wT, q_ws, k_ws, vT_ws);
    attn_kernel<<<dim3(16, 32), 256, 0, stream>>>(q_ws, k_ws, vT_ws, at_ws);
    gemm_final_kernel<<<dim3(8, 64), 256, 0, stream>>>(at_ws, wT + 3 * 1048576, out, bp);
}

// Round 7
// 186.514 us; speedup vs baseline: 1.2257x; 1.2257x over previous
//
#include <hip/hip_runtime.h>
#include <hip/hip_bf16.h>

// Problem: B=2, N=2048, C=1024, H=16, D=64, CHUNK=128, nk=16
// out = ( sum_chunks softmax_chunk( (xWq)(xWk)^T * D^-0.5 ) (xWv) ) Wp + bp

typedef __attribute__((ext_vector_type(4))) float f32x4;
typedef __attribute__((ext_vector_type(8))) short short8;  // 8 bf16 = 4 VGPRs

static __device__ __forceinline__ unsigned short f2bfu(float f) {
    union { __hip_bfloat16 b; unsigned short u; } cv;
    cv.b = __float2bfloat16(f);
    return cv.u;
}
static __device__ __forceinline__ __hip_bfloat16 f2bf(float f) {
    return __float2bfloat16(f);
}
// pack hi16(a),hi16(b) with round-half-up: 2 adds + 1 v_perm (vs ~11 ops for RNE pair)
static __device__ __forceinline__ unsigned int pkrnd(float a, float b) {
    union { float f; unsigned int u; } ua, ub;
    ua.f = a; ub.f = b;
    return __builtin_amdgcn_perm(ub.u + 0x8000u, ua.u + 0x8000u, 0x07060302u);
}
// async global->LDS DMA, 16B per lane, lands at wave-uniform lds base + lane*16
static __device__ __forceinline__ void gload_lds16(const __hip_bfloat16* g, __hip_bfloat16* l) {
    __builtin_amdgcn_global_load_lds(
        (const __attribute__((address_space(1))) void*)g,
        (__attribute__((address_space(3))) void*)l, 16, 0, 0);
}

// ---------------- fused conversion kernel ----------------
// blocks [0,4096): x fp32->bf16 (float4/thread). blocks [4096,8192): W->W^T bf16.
__global__ __launch_bounds__(256) void conv_fused_kernel(
    const float* __restrict__ x, __hip_bfloat16* __restrict__ xb,
    const float* __restrict__ w0, const float* __restrict__ w1,
    const float* __restrict__ w2, const float* __restrict__ w3,
    __hip_bfloat16* __restrict__ wt) {
    const int t = threadIdx.x;
    if (blockIdx.x < 4096) {
        int i = blockIdx.x * 256 + t;
        float4 v = ((const float4*)x)[i];
        ushort4 o;
        o.x = f2bfu(v.x); o.y = f2bfu(v.y); o.z = f2bfu(v.z); o.w = f2bfu(v.w);
        ((ushort4*)xb)[i] = o;
    } else {
        __shared__ float tile[32][33];
        int zz = blockIdx.x - 4096;
        int z = zz >> 10, byi = (zz >> 5) & 31, bxi = zz & 31;
        const float* W = (z == 0) ? w0 : (z == 1) ? w1 : (z == 2) ? w2 : w3;
        __hip_bfloat16* out = wt + (size_t)z * 1048576;
        const int tx = t & 31, ty = t >> 5;  // 32 x 8
        const int r0 = byi * 32, c0 = bxi * 32;
        for (int j = 0; j < 4; ++j)
            tile[ty + j * 8][tx] = W[(size_t)(r0 + ty + j * 8) * 1024 + c0 + tx];
        __syncthreads();
        for (int j = 0; j < 4; ++j)
            out[(size_t)(c0 + ty + j * 8) * 1024 + r0 + tx] = f2bf(tile[tx][ty + j * 8]);
    }
}

// ---------------- QKV GEMM (global_load_lds + XOR-swizzled LDS, m97 shape) ----------------
// z=0 -> q_ws (pre-scaled by D^-0.5*log2e), z=1 -> k_ws, z=2 -> vT_ws [B,H,D,Nperm].
// LDS tiles 128x32 unpadded; physical chunk p of row r holds logical chunk p^((r>>1)&3).
__global__ __launch_bounds__(256) void gemm_qkv_kernel(
    const __hip_bfloat16* __restrict__ A, const __hip_bfloat16* __restrict__ WT,
    __hip_bfloat16* __restrict__ q_ws, __hip_bfloat16* __restrict__ k_ws,
    __hip_bfloat16* __restrict__ vT_ws) {
    const int t = threadIdx.x;
    const int lane = t & 63, w = t >> 6;
    const int quad = lane >> 4, l16 = lane & 15;
    const int wm = w >> 1, wn = w & 1;
    const int n0 = blockIdx.x * 128, m0 = blockIdx.y * 128;
    const int z = blockIdx.z;
    const __hip_bfloat16* Bt = WT + (size_t)z * 1048576;

    __shared__ __align__(16) __hip_bfloat16 As[128 * 32];
    __shared__ __align__(16) __hip_bfloat16 Bs[128 * 32];

    const int rS = t >> 2;                                   // inst 0 row (inst1: +64)
    const int cS = ((t & 3) ^ ((t >> 3) & 3)) * 8;           // lane-constant swizzled chunk
    const __hip_bfloat16* gA = A + (size_t)(m0 + rS) * 1024 + cS;
    const __hip_bfloat16* gB = Bt + (size_t)(n0 + rS) * 1024 + cS;
    __hip_bfloat16* lA = As + (t & 192) * 8;                 // wave base, inst0
    __hip_bfloat16* lB = Bs + (t & 192) * 8;
    const int csw = (quad ^ ((l16 >> 1) & 3)) * 8;           // frag-read swizzled chunk

    f32x4 acc[4][4];
    const f32x4 z4 = {0.f, 0.f, 0.f, 0.f};
    for (int i = 0; i < 4; ++i)
        for (int j = 0; j < 4; ++j) acc[i][j] = z4;

    for (int kk = 0; kk < 32; ++kk) {
        const int k0 = kk * 32;
        __syncthreads();
        gload_lds16(gA + k0, lA);
        gload_lds16(gA + 64 * 1024 + k0, lA + 256 * 8);
        gload_lds16(gB + k0, lB);
        gload_lds16(gB + 64 * 1024 + k0, lB + 256 * 8);
        __syncthreads();
        short8 af[4], bf[4];
        for (int i = 0; i < 4; ++i)
            af[i] = *(const short8*)(As + (wm * 64 + i * 16 + l16) * 32 + csw);
        for (int j = 0; j < 4; ++j)
            bf[j] = *(const short8*)(Bs + (wn * 64 + j * 16 + l16) * 32 + csw);
        for (int i = 0; i < 4; ++i)
            for (int j = 0; j < 4; ++j)
                acc[i][j] = __builtin_amdgcn_mfma_f32_16x16x32_bf16(af[i], bf[j], acc[i][j], 0, 0, 0);
    }

    const int r0 = m0 + wm * 64, c0 = n0 + wn * 64;
    if (z < 2) {
        const float sc = (z == 0) ? 0.18033688f : 1.0f;  // 0.125 * log2(e)
        __hip_bfloat16* dst = (z == 0) ? q_ws : k_ws;
        for (int i = 0; i < 4; ++i) {
            int rowb = r0 + i * 16 + quad * 4;
            for (int j = 0; j < 4; ++j) {
                int col = c0 + j * 16 + l16;
                for (int rg = 0; rg < 4; ++rg)
                    dst[(size_t)(rowb + rg) * 1024 + col] = f2bf(acc[i][j][rg] * sc);
            }
        }
    } else {
        // token c (within 128-chunk) -> V column (c&~31)|(((c>>2)&3)<<3)|(((c>>4)&1)<<2)|(c&3)
        int b = r0 >> 11;
        for (int i = 0; i < 4; ++i) {
            int n_ = (r0 + i * 16 + quad * 4) & 2047;
            int nb = n_ & ~127;
            int c = n_ & 127;  // c&3 == 0 here
            int vcol = (c & ~31) | (((c >> 2) & 3) << 3) | (((c >> 4) & 1) << 2);
            for (int j = 0; j < 4; ++j) {
                int col = c0 + j * 16 + l16;
                int h = col >> 6, d = col & 63;
                ushort4 o;
                o.x = f2bfu(acc[i][j][0]); o.y = f2bfu(acc[i][j][1]);
                o.z = f2bfu(acc[i][j][2]); o.w = f2bfu(acc[i][j][3]);
                *(ushort4*)(vT_ws + (size_t)((b * 16 + h) * 64 + d) * 2048 + nb + vcol) = o;
            }
        }
    }
}

// ---------------- final GEMM (64-row tiles, DMA staging, fp32 out + bias) ----------------
__global__ __launch_bounds__(256) void gemm_final_kernel(
    const __hip_bfloat16* __restrict__ A, const __hip_bfloat16* __restrict__ Bt,
    float* __restrict__ outF, const float* __restrict__ bias) {
    const int t = threadIdx.x;
    const int lane = t & 63, w = t >> 6;
    const int quad = lane >> 4, l16 = lane & 15;
    const int n0 = blockIdx.x * 128, m0 = blockIdx.y * 64;

    __shared__ __align__(16) __hip_bfloat16 As[64 * 32];
    __shared__ __align__(16) __hip_bfloat16 Bs[128 * 32];

    const int rS = t >> 2;
    const int cS = ((t & 3) ^ ((t >> 3) & 3)) * 8;
    const __hip_bfloat16* gA = A + (size_t)(m0 + rS) * 1024 + cS;
    const __hip_bfloat16* gB = Bt + (size_t)(n0 + rS) * 1024 + cS;
    __hip_bfloat16* lA = As + (t & 192) * 8;
    __hip_bfloat16* lB = Bs + (t & 192) * 8;
    const int csw = (quad ^ ((l16 >> 1) & 3)) * 8;

    f32x4 acc[4][2];
    const f32x4 z4 = {0.f, 0.f, 0.f, 0.f};
    for (int i = 0; i < 4; ++i)
        for (int j = 0; j < 2; ++j) acc[i][j] = z4;

    for (int kk = 0; kk < 32; ++kk) {
        const int k0 = kk * 32;
        __syncthreads();
        gload_lds16(gA + k0, lA);
        gload_lds16(gB + k0, lB);
        gload_lds16(gB + 64 * 1024 + k0, lB + 256 * 8);
        __syncthreads();
        short8 af[4], bf[2];
        for (int i = 0; i < 4; ++i)
            af[i] = *(const short8*)(As + (i * 16 + l16) * 32 + csw);
        for (int j = 0; j < 2; ++j)
            bf[j] = *(const short8*)(Bs + (w * 32 + j * 16 + l16) * 32 + csw);
        for (int i = 0; i < 4; ++i)
            for (int j = 0; j < 2; ++j)
                acc[i][j] = __builtin_amdgcn_mfma_f32_16x16x32_bf16(af[i], bf[j], acc[i][j], 0, 0, 0);
    }

    for (int i = 0; i < 4; ++i) {
        int rowb = m0 + i * 16 + quad * 4;
        for (int j = 0; j < 2; ++j) {
            int col = n0 + w * 32 + j * 16 + l16;
            float bv = bias[col];
            for (int rg = 0; rg < 4; ++rg)
                outF[(size_t)(rowb + rg) * 1024 + col] = acc[i][j][rg] + bv;
        }
    }
}

// ---------------- fused attention (2x2 wave split; prefetch = load+ds_write at loop top) ----------------
// grid (16 q-tiles of 128, 32 bh), block 256 (4 waves). Wave (qg=w&1, kg=w>>1):
// 64 q x 64 keys per chunk -> each wave reads only HALF of K and V frags.
// Prefetch into buf^1 stages IMMEDIATELY (short VGPR live range — round-5-proven,
// no scratch spill; round 6's register-held prefetch caused 200 MB spill traffic).
// Softmax denominator: in-wave reduce + ps exchange between kg-pairs (barrier #1).
// O partial per kg; cross-wave add once in epilogue. K/V unpadded + XOR-swizzled.
__global__ __launch_bounds__(256, 2) void attn_kernel(
    const __hip_bfloat16* __restrict__ q_ws, const __hip_bfloat16* __restrict__ k_ws,
    const __hip_bfloat16* __restrict__ vT_ws, __hip_bfloat16* __restrict__ attn_ws) {
    const int t = threadIdx.x, lane = t & 63, w = t >> 6;
    const int quad = lane >> 4, l16 = lane & 15;
    const int qg = w & 1, kg = w >> 1;
    const int qt = blockIdx.x;   // 0..15 (128 q each)
    const int bh = blockIdx.y;   // 0..31
    const int b = bh >> 4, h = bh & 15;
    const int q0 = qt * 128;

    // buf c (c=0,1): Ks @ c*32768 [128][64] (swz p=c^(r&7)), Vt @ c*32768+16384 [64][128]
    // (swz p=c^(r&15)); ps @ 65536: float[kg2][8][16]
    __shared__ __align__(16) char smem[66048];
    float* ps = (float*)(smem + 65536);

    // staging lane constants
    const int sgK = t & 7, rKl = t >> 3;    // K rows rKl + it*32
    const int pK = sgK ^ (rKl & 7);
    const int sgV = t & 15, rVl = t >> 4;   // V rows rVl + it*16
    const int pV = sgV ^ (rVl & 15);
    const __hip_bfloat16* gK = k_ws + (size_t)(b * 2048) * 1024 + h * 64;
    const __hip_bfloat16* gV = vT_ws + (size_t)(bh * 64) * 2048;

    // Q fragments (B-operand of S^T = K Q^T): 4 q-tiles x 2 k-blocks, register-resident
    short8 qf[4][2];
#pragma unroll
    for (int j = 0; j < 4; ++j)
#pragma unroll
        for (int kt = 0; kt < 2; ++kt)
            qf[j][kt] = *(const short8*)(q_ws + (size_t)(b * 2048 + q0 + qg * 64 + j * 16 + l16) * 1024 + h * 64 + kt * 32 + quad * 8);

    const f32x4 z4 = {0.f, 0.f, 0.f, 0.f};
    f32x4 O[4][4];  // O^T partial (this wave's 64 keys): [q-tile j][d-tile dt]
#pragma unroll
    for (int j = 0; j < 4; ++j)
#pragma unroll
        for (int dt = 0; dt < 4; ++dt) O[j][dt] = z4;

    // ---- stage chunk 0 into buffer 0 ----
    {
        __hip_bfloat16* Ks0 = (__hip_bfloat16*)smem;
        __hip_bfloat16* Vt0 = (__hip_bfloat16*)(smem + 16384);
#pragma unroll
        for (int it = 0; it < 4; ++it) {
            int r = it * 32 + rKl;
            uint4 v = *(const uint4*)(gK + (size_t)r * 1024 + sgK * 8);
            *(uint4*)(Ks0 + r * 64 + pK * 8) = v;
        }
#pragma unroll
        for (int it = 0; it < 4; ++it) {
            int r = it * 16 + rVl;
            uint4 v = *(const uint4*)(gV + (size_t)r * 2048 + sgV * 8);
            *(uint4*)(Vt0 + r * 128 + pV * 8) = v;
        }
    }
    __syncthreads();

    for (int ck = 0; ck < 16; ++ck) {
        const int cur = ck & 1;
        __hip_bfloat16* Ks = (__hip_bfloat16*)(smem + cur * 32768);
        __hip_bfloat16* Vt = (__hip_bfloat16*)(smem + cur * 32768 + 16384);

        // prefetch next chunk into buf^1 NOW (load -> immediate ds_write; buf^1 was
        // fully consumed before the previous iteration's end barrier)
        if (ck < 15) {
            __hip_bfloat16* Ksn = (__hip_bfloat16*)(smem + (cur ^ 1) * 32768);
            __hip_bfloat16* Vtn = (__hip_bfloat16*)(smem + (cur ^ 1) * 32768 + 16384);
#pragma unroll
            for (int it = 0; it < 4; ++it) {
                uint4 v = *(const uint4*)(gK + (size_t)((ck + 1) * 128 + it * 32 + rKl) * 1024 + sgK * 8);
                *(uint4*)(Ksn + (it * 32 + rKl) * 64 + pK * 8) = v;
            }
#pragma unroll
            for (int it = 0; it < 4; ++it) {
                uint4 v = *(const uint4*)(gV + (size_t)(it * 16 + rVl) * 2048 + (ck + 1) * 128 + sgV * 8);
                *(uint4*)(Vtn + (it * 16 + rVl) * 128 + pV * 8) = v;
            }
        }

        // S^T = K Q^T : this wave's 4 key-tiles x 4 q-tiles, K-dim 64
        f32x4 s[4][4];
#pragma unroll
        for (int j = 0; j < 4; ++j)
#pragma unroll
            for (int i = 0; i < 4; ++i) s[j][i] = z4;
#pragma unroll
        for (int kt = 0; kt < 2; ++kt) {
            short8 kf[4];
#pragma unroll
            for (int i = 0; i < 4; ++i)
                kf[i] = *(const short8*)(Ks + (kg * 64 + i * 16 + l16) * 64 + (((kt * 4 + quad) ^ (l16 & 7)) * 8));
#pragma unroll
            for (int i = 0; i < 4; ++i)
#pragma unroll
                for (int j = 0; j < 4; ++j)
                    s[j][i] = __builtin_amdgcn_mfma_f32_16x16x32_bf16(kf[i], qf[j][kt], s[j][i], 0, 0, 0);
        }

        // exp (no max-sub: args bounded ~|4|), in-wave sum over this wave's 64 keys
        float own[4];
#pragma unroll
        for (int j = 0; j < 4; ++j) {
            float sum = 0.f;
#pragma unroll
            for (int i = 0; i < 4; ++i) {
                f32x4 p;
                p[0] = __builtin_amdgcn_exp2f(s[j][i][0]);
                p[1] = __builtin_amdgcn_exp2f(s[j][i][1]);
                p[2] = __builtin_amdgcn_exp2f(s[j][i][2]);
                p[3] = __builtin_amdgcn_exp2f(s[j][i][3]);
                s[j][i] = p;
                sum += (p[0] + p[1]) + (p[2] + p[3]);
            }
            sum += __shfl_xor(sum, 16, 64);
            sum += __shfl_xor(sum, 32, 64);
            own[j] = sum;
        }
        if (quad == 0) {
#pragma unroll
            for (int j = 0; j < 4; ++j)
                ps[(kg * 8 + qg * 4 + j) * 16 + l16] = own[j];
        }
        __syncthreads();  // #1: ps visible (prefetch ds_writes also drain here, harmless)

        float inv[4];
#pragma unroll
        for (int j = 0; j < 4; ++j)
            inv[j] = 1.0f / (own[j] + ps[((kg ^ 1) * 8 + qg * 4 + j) * 16 + l16]);

        // O^T += V^T P^T over this wave's 64 keys (2 K-blocks of 32)
#pragma unroll
        for (int ktl = 0; ktl < 2; ++ktl) {
            short8 bfr[4];
#pragma unroll
            for (int j = 0; j < 4; ++j) {
                const int i0 = 2 * ktl, i1 = 2 * ktl + 1;
                union { uint4 u; short8 s8; } bb;
                bb.u.x = pkrnd(s[j][i0][0] * inv[j], s[j][i0][1] * inv[j]);
                bb.u.y = pkrnd(s[j][i0][2] * inv[j], s[j][i0][3] * inv[j]);
                bb.u.z = pkrnd(s[j][i1][0] * inv[j], s[j][i1][1] * inv[j]);
                bb.u.w = pkrnd(s[j][i1][2] * inv[j], s[j][i1][3] * inv[j]);
                bfr[j] = bb.s8;
            }
#pragma unroll
            for (int dt = 0; dt < 4; ++dt) {
                short8 vf = *(const short8*)(Vt + (dt * 16 + l16) * 128 + ((((kg * 2 + ktl) * 4 + quad) ^ l16) * 8));
#pragma unroll
                for (int j = 0; j < 4; ++j)
                    O[j][dt] = __builtin_amdgcn_mfma_f32_16x16x32_bf16(vf, bfr[j], O[j][dt], 0, 0, 0);
            }
        }
        __syncthreads();  // #2: all waves done with cur (it becomes next prefetch target)
    }

    // ---- epilogue: cross-kg O add, then LDS transpose to row-major ----
    if (kg == 1) {
        float* Of = (float*)(smem + qg * 16384);
#pragma unroll
        for (int dt = 0; dt < 4; ++dt)
#pragma unroll
            for (int j = 0; j < 4; ++j)
                *(f32x4*)(Of + ((size_t)((dt * 4 + j) * 64 + quad * 16 + l16)) * 4) = O[j][dt];
    }
    __syncthreads();
    if (kg == 0) {
        float* Of = (float*)(smem + qg * 16384);
        __hip_bfloat16* T = (__hip_bfloat16*)(smem + 32768);  // [128][72]
#pragma unroll
        for (int dt = 0; dt < 4; ++dt)
#pragma unroll
            for (int j = 0; j < 4; ++j) {
                f32x4 o2 = *(const f32x4*)(Of + ((size_t)((dt * 4 + j) * 64 + quad * 16 + l16)) * 4);
                f32x4 oo = O[j][dt] + o2;
                unsigned int w0 = pkrnd(oo[0], oo[1]);
                unsigned int w1 = pkrnd(oo[2], oo[3]);
                int r = qg * 64 + j * 16 + l16;
                *(unsigned int*)(T + r * 72 + dt * 16 + quad * 4) = w0;
                *(unsigned int*)(T + r * 72 + dt * 16 + quad * 4 + 2) = w1;
            }
    }
    __syncthreads();
    {
        const __hip_bfloat16* T = (const __hip_bfloat16*)(smem + 32768);
#pragma unroll
        for (int it = 0; it < 4; ++it) {
            int idx = it * 256 + t;
            int q = idx >> 3, seg = idx & 7;
            uint4 vv = *(const uint4*)(T + q * 72 + seg * 8);
            *(uint4*)(attn_ws + (size_t)(b * 2048 + q0 + q) * 1024 + h * 64 + seg * 8) = vv;
        }
    }
}

// ---------------- launch ----------------
extern "C" void kernel_launch(void* const* d_in, const int* in_sizes, int n_in,
                              void* d_out, int out_size, void* d_ws, size_t ws_size,
                              hipStream_t stream) {
    const float* x  = (const float*)d_in[0];
    const float* Wq = (const float*)d_in[1];
    const float* Wk = (const float*)d_in[2];
    const float* Wv = (const float*)d_in[3];
    const float* Wp = (const float*)d_in[4];
    const float* bp = (const float*)d_in[5];
    float* out = (float*)d_out;

    char* ws = (char*)d_ws;
    __hip_bfloat16* xb    = (__hip_bfloat16*)(ws);              // 8 MB
    __hip_bfloat16* wT    = (__hip_bfloat16*)(ws + 8388608);    // 8 MB
    __hip_bfloat16* q_ws  = (__hip_bfloat16*)(ws + 16777216);   // 8 MB (pre-scaled)
    __hip_bfloat16* k_ws  = (__hip_bfloat16*)(ws + 25165824);   // 8 MB
    __hip_bfloat16* vT_ws = (__hip_bfloat16*)(ws + 33554432);   // 8 MB [B,H,D,Nperm]
    __hip_bfloat16* at_ws = (__hip_bfloat16*)(ws + 41943040);   // 8 MB

    conv_fused_kernel<<<8192, 256, 0, stream>>>(x, xb, Wq, Wk, Wv, Wp, wT);
    gemm_qkv_kernel<<<dim3(8, 32, 3), 256, 0, stream>>>(xb, wT, q_ws, k_ws, vT_ws);
    attn_kernel<<<dim3(16, 32), 256, 0, stream>>>(q_ws, k_ws, vT_ws, at_ws);
    gemm_final_kernel<<<dim3(8, 64), 256, 0, stream>>>(at_ws, wT + 3 * 1048576, out, bp);
}

// Round 8
// 184.089 us; speedup vs baseline: 1.2419x; 1.0132x over previous
//
#include <hip/hip_runtime.h>
#include <hip/hip_bf16.h>

// Problem: B=2, N=2048, C=1024, H=16, D=64, CHUNK=128, nk=16
// out = ( sum_chunks softmax_chunk( (xWq)(xWk)^T * D^-0.5 ) (xWv) ) Wp + bp

typedef __attribute__((ext_vector_type(4))) float f32x4;
typedef __attribute__((ext_vector_type(8))) short short8;  // 8 bf16 = 4 VGPRs

static __device__ __forceinline__ unsigned short f2bfu(float f) {
    union { __hip_bfloat16 b; unsigned short u; } cv;
    cv.b = __float2bfloat16(f);
    return cv.u;
}
static __device__ __forceinline__ __hip_bfloat16 f2bf(float f) {
    return __float2bfloat16(f);
}
// pack hi16(a),hi16(b) with round-half-up: 2 adds + 1 v_perm (vs ~11 ops for RNE pair)
static __device__ __forceinline__ unsigned int pkrnd(float a, float b) {
    union { float f; unsigned int u; } ua, ub;
    ua.f = a; ub.f = b;
    return __builtin_amdgcn_perm(ub.u + 0x8000u, ua.u + 0x8000u, 0x07060302u);
}
// async global->LDS DMA, 16B per lane, lands at wave-uniform lds base + lane*16
static __device__ __forceinline__ void gload_lds16(const __hip_bfloat16* g, __hip_bfloat16* l) {
    __builtin_amdgcn_global_load_lds(
        (const __attribute__((address_space(1))) void*)g,
        (__attribute__((address_space(3))) void*)l, 16, 0, 0);
}

// ---------------- fused conversion kernel ----------------
// blocks [0,4096): x fp32->bf16 (float4/thread). blocks [4096,8192): W->W^T bf16.
__global__ __launch_bounds__(256) void conv_fused_kernel(
    const float* __restrict__ x, __hip_bfloat16* __restrict__ xb,
    const float* __restrict__ w0, const float* __restrict__ w1,
    const float* __restrict__ w2, const float* __restrict__ w3,
    __hip_bfloat16* __restrict__ wt) {
    const int t = threadIdx.x;
    if (blockIdx.x < 4096) {
        int i = blockIdx.x * 256 + t;
        float4 v = ((const float4*)x)[i];
        ushort4 o;
        o.x = f2bfu(v.x); o.y = f2bfu(v.y); o.z = f2bfu(v.z); o.w = f2bfu(v.w);
        ((ushort4*)xb)[i] = o;
    } else {
        __shared__ float tile[32][33];
        int zz = blockIdx.x - 4096;
        int z = zz >> 10, byi = (zz >> 5) & 31, bxi = zz & 31;
        const float* W = (z == 0) ? w0 : (z == 1) ? w1 : (z == 2) ? w2 : w3;
        __hip_bfloat16* out = wt + (size_t)z * 1048576;
        const int tx = t & 31, ty = t >> 5;  // 32 x 8
        const int r0 = byi * 32, c0 = bxi * 32;
        for (int j = 0; j < 4; ++j)
            tile[ty + j * 8][tx] = W[(size_t)(r0 + ty + j * 8) * 1024 + c0 + tx];
        __syncthreads();
        for (int j = 0; j < 4; ++j)
            out[(size_t)(c0 + ty + j * 8) * 1024 + r0 + tx] = f2bf(tile[tx][ty + j * 8]);
    }
}

// ---------------- QKV GEMM (global_load_lds + XOR-swizzled LDS, m97 shape) ----------------
// z=0 -> q_ws (pre-scaled by D^-0.5*log2e), z=1 -> k_ws, z=2 -> vT_ws [B,H,D,Nperm].
// LDS tiles 128x32 unpadded; physical chunk p of row r holds logical chunk p^((r>>1)&3).
__global__ __launch_bounds__(256) void gemm_qkv_kernel(
    const __hip_bfloat16* __restrict__ A, const __hip_bfloat16* __restrict__ WT,
    __hip_bfloat16* __restrict__ q_ws, __hip_bfloat16* __restrict__ k_ws,
    __hip_bfloat16* __restrict__ vT_ws) {
    const int t = threadIdx.x;
    const int lane = t & 63, w = t >> 6;
    const int quad = lane >> 4, l16 = lane & 15;
    const int wm = w >> 1, wn = w & 1;
    const int n0 = blockIdx.x * 128, m0 = blockIdx.y * 128;
    const int z = blockIdx.z;
    const __hip_bfloat16* Bt = WT + (size_t)z * 1048576;

    __shared__ __align__(16) __hip_bfloat16 As[128 * 32];
    __shared__ __align__(16) __hip_bfloat16 Bs[128 * 32];

    const int rS = t >> 2;                                   // inst 0 row (inst1: +64)
    const int cS = ((t & 3) ^ ((t >> 3) & 3)) * 8;           // lane-constant swizzled chunk
    const __hip_bfloat16* gA = A + (size_t)(m0 + rS) * 1024 + cS;
    const __hip_bfloat16* gB = Bt + (size_t)(n0 + rS) * 1024 + cS;
    __hip_bfloat16* lA = As + (t & 192) * 8;                 // wave base, inst0
    __hip_bfloat16* lB = Bs + (t & 192) * 8;
    const int csw = (quad ^ ((l16 >> 1) & 3)) * 8;           // frag-read swizzled chunk

    f32x4 acc[4][4];
    const f32x4 z4 = {0.f, 0.f, 0.f, 0.f};
    for (int i = 0; i < 4; ++i)
        for (int j = 0; j < 4; ++j) acc[i][j] = z4;

    for (int kk = 0; kk < 32; ++kk) {
        const int k0 = kk * 32;
        __syncthreads();
        gload_lds16(gA + k0, lA);
        gload_lds16(gA + 64 * 1024 + k0, lA + 256 * 8);
        gload_lds16(gB + k0, lB);
        gload_lds16(gB + 64 * 1024 + k0, lB + 256 * 8);
        __syncthreads();
        short8 af[4], bf[4];
        for (int i = 0; i < 4; ++i)
            af[i] = *(const short8*)(As + (wm * 64 + i * 16 + l16) * 32 + csw);
        for (int j = 0; j < 4; ++j)
            bf[j] = *(const short8*)(Bs + (wn * 64 + j * 16 + l16) * 32 + csw);
        for (int i = 0; i < 4; ++i)
            for (int j = 0; j < 4; ++j)
                acc[i][j] = __builtin_amdgcn_mfma_f32_16x16x32_bf16(af[i], bf[j], acc[i][j], 0, 0, 0);
    }

    const int r0 = m0 + wm * 64, c0 = n0 + wn * 64;
    if (z < 2) {
        const float sc = (z == 0) ? 0.18033688f : 1.0f;  // 0.125 * log2(e)
        __hip_bfloat16* dst = (z == 0) ? q_ws : k_ws;
        for (int i = 0; i < 4; ++i) {
            int rowb = r0 + i * 16 + quad * 4;
            for (int j = 0; j < 4; ++j) {
                int col = c0 + j * 16 + l16;
                for (int rg = 0; rg < 4; ++rg)
                    dst[(size_t)(rowb + rg) * 1024 + col] = f2bf(acc[i][j][rg] * sc);
            }
        }
    } else {
        // token c (within 128-chunk) -> V column (c&~31)|(((c>>2)&3)<<3)|(((c>>4)&1)<<2)|(c&3)
        int b = r0 >> 11;
        for (int i = 0; i < 4; ++i) {
            int n_ = (r0 + i * 16 + quad * 4) & 2047;
            int nb = n_ & ~127;
            int c = n_ & 127;  // c&3 == 0 here
            int vcol = (c & ~31) | (((c >> 2) & 3) << 3) | (((c >> 4) & 1) << 2);
            for (int j = 0; j < 4; ++j) {
                int col = c0 + j * 16 + l16;
                int h = col >> 6, d = col & 63;
                ushort4 o;
                o.x = f2bfu(acc[i][j][0]); o.y = f2bfu(acc[i][j][1]);
                o.z = f2bfu(acc[i][j][2]); o.w = f2bfu(acc[i][j][3]);
                *(ushort4*)(vT_ws + (size_t)((b * 16 + h) * 64 + d) * 2048 + nb + vcol) = o;
            }
        }
    }
}

// ---------------- final GEMM (64-row tiles, DMA staging, fp32 out + bias) ----------------
__global__ __launch_bounds__(256) void gemm_final_kernel(
    const __hip_bfloat16* __restrict__ A, const __hip_bfloat16* __restrict__ Bt,
    float* __restrict__ outF, const float* __restrict__ bias) {
    const int t = threadIdx.x;
    const int lane = t & 63, w = t >> 6;
    const int quad = lane >> 4, l16 = lane & 15;
    const int n0 = blockIdx.x * 128, m0 = blockIdx.y * 64;

    __shared__ __align__(16) __hip_bfloat16 As[64 * 32];
    __shared__ __align__(16) __hip_bfloat16 Bs[128 * 32];

    const int rS = t >> 2;
    const int cS = ((t & 3) ^ ((t >> 3) & 3)) * 8;
    const __hip_bfloat16* gA = A + (size_t)(m0 + rS) * 1024 + cS;
    const __hip_bfloat16* gB = Bt + (size_t)(n0 + rS) * 1024 + cS;
    __hip_bfloat16* lA = As + (t & 192) * 8;
    __hip_bfloat16* lB = Bs + (t & 192) * 8;
    const int csw = (quad ^ ((l16 >> 1) & 3)) * 8;

    f32x4 acc[4][2];
    const f32x4 z4 = {0.f, 0.f, 0.f, 0.f};
    for (int i = 0; i < 4; ++i)
        for (int j = 0; j < 2; ++j) acc[i][j] = z4;

    for (int kk = 0; kk < 32; ++kk) {
        const int k0 = kk * 32;
        __syncthreads();
        gload_lds16(gA + k0, lA);
        gload_lds16(gB + k0, lB);
        gload_lds16(gB + 64 * 1024 + k0, lB + 256 * 8);
        __syncthreads();
        short8 af[4], bf[2];
        for (int i = 0; i < 4; ++i)
            af[i] = *(const short8*)(As + (i * 16 + l16) * 32 + csw);
        for (int j = 0; j < 2; ++j)
            bf[j] = *(const short8*)(Bs + (w * 32 + j * 16 + l16) * 32 + csw);
        for (int i = 0; i < 4; ++i)
            for (int j = 0; j < 2; ++j)
                acc[i][j] = __builtin_amdgcn_mfma_f32_16x16x32_bf16(af[i], bf[j], acc[i][j], 0, 0, 0);
    }

    for (int i = 0; i < 4; ++i) {
        int rowb = m0 + i * 16 + quad * 4;
        for (int j = 0; j < 2; ++j) {
            int col = n0 + w * 32 + j * 16 + l16;
            float bv = bias[col];
            for (int rg = 0; rg < 4; ++rg)
                outF[(size_t)(rowb + rg) * 1024 + col] = acc[i][j][rg] + bv;
        }
    }
}

// ---------------- fused attention (512-thread blocks: 4x2 wave split) ----------------
// grid (16 q-tiles of 128, 32 bh), block 512 (8 waves) -> 2 blocks/CU = 16 waves/CU
// (4 waves/SIMD, 2x round 7) while staging stays 2 tiles/chunk/CU. Wave (qg=w&3,
// kg=w>>2): 32 q x 64 keys. Per-wave regs halve vs round 7 (s[2][4], O[2][4]) so
// 4 waves/EU fit. Softmax denom: in-wave reduce + ps exchange between kg-pairs.
// O partial per kg, cross-wave add in epilogue. K/V unpadded + XOR-swizzled,
// double-buffered; prefetch = load + immediate ds_write at loop top (spill-safe).
__global__ __launch_bounds__(512, 4) void attn_kernel(
    const __hip_bfloat16* __restrict__ q_ws, const __hip_bfloat16* __restrict__ k_ws,
    const __hip_bfloat16* __restrict__ vT_ws, __hip_bfloat16* __restrict__ attn_ws) {
    const int t = threadIdx.x, lane = t & 63, w = t >> 6;
    const int quad = lane >> 4, l16 = lane & 15;
    const int qg = w & 3, kg = w >> 2;
    const int qt_ = blockIdx.x;  // 0..15 (128 q each)
    const int bh = blockIdx.y;   // 0..31
    const int b = bh >> 4, h = bh & 15;
    const int q0 = qt_ * 128;

    // buf c: Ks @ c*32768 [128][64] (swz p=c^(r&7)), Vt @ c*32768+16384 [64][128]
    // (swz p=c^(r&15)); ps @ 65536: float[kg2][qg4*qt2][16]
    __shared__ __align__(16) char smem[66560];
    float* ps = (float*)(smem + 65536);

    // staging lane constants (512 threads: 2 uint4 each for K, 2 for V)
    const int sgK = t & 7, rKl = t >> 3;    // K rows rKl + it*64
    const int pK = sgK ^ (rKl & 7);
    const int sgV = t & 15, rVl = t >> 4;   // V rows rVl + it*32
    const int pV = sgV ^ (rVl & 15);
    const __hip_bfloat16* gK = k_ws + (size_t)(b * 2048) * 1024 + h * 64;
    const __hip_bfloat16* gV = vT_ws + (size_t)(bh * 64) * 2048;

    // Q fragments (B-operand of S^T = K Q^T): 2 q-tiles x 2 k-blocks
    short8 qf[2][2];
#pragma unroll
    for (int qt = 0; qt < 2; ++qt)
#pragma unroll
        for (int kt = 0; kt < 2; ++kt)
            qf[qt][kt] = *(const short8*)(q_ws + (size_t)(b * 2048 + q0 + qg * 32 + qt * 16 + l16) * 1024 + h * 64 + kt * 32 + quad * 8);

    const f32x4 z4 = {0.f, 0.f, 0.f, 0.f};
    f32x4 O[2][4];  // O^T partial (this wave's 64 keys): [q-tile][d-tile]
#pragma unroll
    for (int qt = 0; qt < 2; ++qt)
#pragma unroll
        for (int dt = 0; dt < 4; ++dt) O[qt][dt] = z4;

    // ---- stage chunk 0 into buffer 0 ----
    {
        __hip_bfloat16* Ks0 = (__hip_bfloat16*)smem;
        __hip_bfloat16* Vt0 = (__hip_bfloat16*)(smem + 16384);
#pragma unroll
        for (int it = 0; it < 2; ++it) {
            int r = it * 64 + rKl;
            uint4 v = *(const uint4*)(gK + (size_t)r * 1024 + sgK * 8);
            *(uint4*)(Ks0 + r * 64 + pK * 8) = v;
        }
#pragma unroll
        for (int it = 0; it < 2; ++it) {
            int r = it * 32 + rVl;
            uint4 v = *(const uint4*)(gV + (size_t)r * 2048 + sgV * 8);
            *(uint4*)(Vt0 + r * 128 + pV * 8) = v;
        }
    }
    __syncthreads();

    for (int ck = 0; ck < 16; ++ck) {
        const int cur = ck & 1;
        __hip_bfloat16* Ks = (__hip_bfloat16*)(smem + cur * 32768);
        __hip_bfloat16* Vt = (__hip_bfloat16*)(smem + cur * 32768 + 16384);

        // prefetch next chunk into buf^1 (load -> immediate ds_write; buf^1 fully
        // consumed before the previous iteration's end barrier)
        if (ck < 15) {
            __hip_bfloat16* Ksn = (__hip_bfloat16*)(smem + (cur ^ 1) * 32768);
            __hip_bfloat16* Vtn = (__hip_bfloat16*)(smem + (cur ^ 1) * 32768 + 16384);
#pragma unroll
            for (int it = 0; it < 2; ++it) {
                int r = it * 64 + rKl;
                uint4 v = *(const uint4*)(gK + (size_t)((ck + 1) * 128 + r) * 1024 + sgK * 8);
                *(uint4*)(Ksn + r * 64 + pK * 8) = v;
            }
#pragma unroll
            for (int it = 0; it < 2; ++it) {
                int r = it * 32 + rVl;
                uint4 v = *(const uint4*)(gV + (size_t)r * 2048 + (ck + 1) * 128 + sgV * 8);
                *(uint4*)(Vtn + r * 128 + pV * 8) = v;
            }
        }

        // S^T = K Q^T : this wave's 4 key-tiles x 2 q-tiles, K-dim 64
        f32x4 s[2][4];
#pragma unroll
        for (int qt = 0; qt < 2; ++qt)
#pragma unroll
            for (int i = 0; i < 4; ++i) s[qt][i] = z4;
#pragma unroll
        for (int kt = 0; kt < 2; ++kt) {
            short8 kf[4];
#pragma unroll
            for (int i = 0; i < 4; ++i)
                kf[i] = *(const short8*)(Ks + (kg * 64 + i * 16 + l16) * 64 + (((kt * 4 + quad) ^ (l16 & 7)) * 8));
#pragma unroll
            for (int i = 0; i < 4; ++i)
#pragma unroll
                for (int qt = 0; qt < 2; ++qt)
                    s[qt][i] = __builtin_amdgcn_mfma_f32_16x16x32_bf16(kf[i], qf[qt][kt], s[qt][i], 0, 0, 0);
        }

        // exp (no max-sub: args bounded ~|4|), in-wave sum over this wave's 64 keys
        float own[2];
#pragma unroll
        for (int qt = 0; qt < 2; ++qt) {
            float sum = 0.f;
#pragma unroll
            for (int i = 0; i < 4; ++i) {
                f32x4 p;
                p[0] = __builtin_amdgcn_exp2f(s[qt][i][0]);
                p[1] = __builtin_amdgcn_exp2f(s[qt][i][1]);
                p[2] = __builtin_amdgcn_exp2f(s[qt][i][2]);
                p[3] = __builtin_amdgcn_exp2f(s[qt][i][3]);
                s[qt][i] = p;
                sum += (p[0] + p[1]) + (p[2] + p[3]);
            }
            sum += __shfl_xor(sum, 16, 64);
            sum += __shfl_xor(sum, 32, 64);
            own[qt] = sum;
        }
        if (quad == 0) {
#pragma unroll
            for (int qt = 0; qt < 2; ++qt)
                ps[(kg * 8 + qg * 2 + qt) * 16 + l16] = own[qt];
        }
        __syncthreads();  // #1: ps visible

        float inv[2];
#pragma unroll
        for (int qt = 0; qt < 2; ++qt)
            inv[qt] = 1.0f / (own[qt] + ps[((kg ^ 1) * 8 + qg * 2 + qt) * 16 + l16]);

        // O^T += V^T P^T over this wave's 64 keys (2 K-blocks of 32)
#pragma unroll
        for (int ktl = 0; ktl < 2; ++ktl) {
            short8 bfr[2];
#pragma unroll
            for (int qt = 0; qt < 2; ++qt) {
                const int i0 = 2 * ktl, i1 = 2 * ktl + 1;
                union { uint4 u; short8 s8; } bb;
                bb.u.x = pkrnd(s[qt][i0][0] * inv[qt], s[qt][i0][1] * inv[qt]);
                bb.u.y = pkrnd(s[qt][i0][2] * inv[qt], s[qt][i0][3] * inv[qt]);
                bb.u.z = pkrnd(s[qt][i1][0] * inv[qt], s[qt][i1][1] * inv[qt]);
                bb.u.w = pkrnd(s[qt][i1][2] * inv[qt], s[qt][i1][3] * inv[qt]);
                bfr[qt] = bb.s8;
            }
#pragma unroll
            for (int dt = 0; dt < 4; ++dt) {
                short8 vf = *(const short8*)(Vt + (dt * 16 + l16) * 128 + ((((kg * 2 + ktl) * 4 + quad) ^ l16) * 8));
#pragma unroll
                for (int qt = 0; qt < 2; ++qt)
                    O[qt][dt] = __builtin_amdgcn_mfma_f32_16x16x32_bf16(vf, bfr[qt], O[qt][dt], 0, 0, 0);
            }
        }
        __syncthreads();  // #2: all waves done with cur (it becomes next prefetch target)
    }

    // ---- epilogue: cross-kg O add, then LDS transpose to row-major ----
    if (kg == 1) {
        float* Of = (float*)(smem + qg * 8192);
#pragma unroll
        for (int dt = 0; dt < 4; ++dt)
#pragma unroll
            for (int qt = 0; qt < 2; ++qt)
                *(f32x4*)(Of + (size_t)((dt * 2 + qt) * 64 + quad * 16 + l16) * 4) = O[qt][dt];
    }
    __syncthreads();
    if (kg == 0) {
        float* Of = (float*)(smem + qg * 8192);
        __hip_bfloat16* T = (__hip_bfloat16*)(smem + 32768);  // [128][72]
#pragma unroll
        for (int dt = 0; dt < 4; ++dt)
#pragma unroll
            for (int qt = 0; qt < 2; ++qt) {
                f32x4 o2 = *(const f32x4*)(Of + (size_t)((dt * 2 + qt) * 64 + quad * 16 + l16) * 4);
                f32x4 oo = O[qt][dt] + o2;
                unsigned int w0 = pkrnd(oo[0], oo[1]);
                unsigned int w1 = pkrnd(oo[2], oo[3]);
                int r = qg * 32 + qt * 16 + l16;
                *(unsigned int*)(T + r * 72 + dt * 16 + quad * 4) = w0;
                *(unsigned int*)(T + r * 72 + dt * 16 + quad * 4 + 2) = w1;
            }
    }
    __syncthreads();
    {
        const __hip_bfloat16* T = (const __hip_bfloat16*)(smem + 32768);
#pragma unroll
        for (int it = 0; it < 2; ++it) {
            int idx = it * 512 + t;
            int q = idx >> 3, seg = idx & 7;
            uint4 vv = *(const uint4*)(T + q * 72 + seg * 8);
            *(uint4*)(attn_ws + (size_t)(b * 2048 + q0 + q) * 1024 + h * 64 + seg * 8) = vv;
        }
    }
}

// ---------------- launch ----------------
extern "C" void kernel_launch(void* const* d_in, const int* in_sizes, int n_in,
                              void* d_out, int out_size, void* d_ws, size_t ws_size,
                              hipStream_t stream) {
    const float* x  = (const float*)d_in[0];
    const float* Wq = (const float*)d_in[1];
    const float* Wk = (const float*)d_in[2];
    const float* Wv = (const float*)d_in[3];
    const float* Wp = (const float*)d_in[4];
    const float* bp = (const float*)d_in[5];
    float* out = (float*)d_out;

    char* ws = (char*)d_ws;
    __hip_bfloat16* xb    = (__hip_bfloat16*)(ws);              // 8 MB
    __hip_bfloat16* wT    = (__hip_bfloat16*)(ws + 8388608);    // 8 MB
    __hip_bfloat16* q_ws  = (__hip_bfloat16*)(ws + 16777216);   // 8 MB (pre-scaled)
    __hip_bfloat16* k_ws  = (__hip_bfloat16*)(ws + 25165824);   // 8 MB
    __hip_bfloat16* vT_ws = (__hip_bfloat16*)(ws + 33554432);   // 8 MB [B,H,D,Nperm]
    __hip_bfloat16* at_ws = (__hip_bfloat16*)(ws + 41943040);   // 8 MB

    conv_fused_kernel<<<8192, 256, 0, stream>>>(x, xb, Wq, Wk, Wv, Wp, wT);
    gemm_qkv_kernel<<<dim3(8, 32, 3), 256, 0, stream>>>(xb, wT, q_ws, k_ws, vT_ws);
    attn_kernel<<<dim3(16, 32), 512, 0, stream>>>(q_ws, k_ws, vT_ws, at_ws);
    gemm_final_kernel<<<dim3(8, 64), 256, 0, stream>>>(at_ws, wT + 3 * 1048576, out, bp);
}